// Round 8
// baseline (869.585 us; speedup 1.0000x reference)
//
#include <hip/hip_runtime.h>
#include <hip/hip_bf16.h>
#include <math.h>

#define HD 2048
#define ID 1024
#define NE 32
#define TOPK 4
#define NTOK 4096
#define NSLOT (NTOK*TOPK)

typedef __attribute__((ext_vector_type(4))) float f32x4;
typedef __attribute__((ext_vector_type(8))) short bf16x8;
typedef unsigned short u16;
typedef unsigned int u32;

union U32x4BF { uint4 u; bf16x8 h; };

static __device__ __forceinline__ u16 f2bf(float f) {
  union { float f; u32 u; } v; v.f = f;
  u32 r = v.u + 0x7fffu + ((v.u >> 16) & 1u);
  return (u16)(r >> 16);
}

static __device__ __forceinline__ u32 cvtpk(float lo, float hi) {
  u32 r;
  asm("v_cvt_pk_bf16_f32 %0, %1, %2" : "=v"(r) : "v"(lo), "v"(hi));
  return r;
}

static __device__ __forceinline__ void barrier_lgkm() {
  asm volatile("s_waitcnt lgkmcnt(0)" ::: "memory");
  __builtin_amdgcn_s_barrier();
}

// ---------------- RMSNorm -> bf16 ----------------
__global__ __launch_bounds__(256) void k_rmsnorm(const float* __restrict__ x,
                                                 const float* __restrict__ w,
                                                 u16* __restrict__ xn) {
  int t = blockIdx.x, tid = threadIdx.x;
  const float* row = x + (size_t)t * HD;
  float4 v0 = ((const float4*)row)[tid*2+0];
  float4 v1 = ((const float4*)row)[tid*2+1];
  float ss = v0.x*v0.x+v0.y*v0.y+v0.z*v0.z+v0.w*v0.w
           + v1.x*v1.x+v1.y*v1.y+v1.z*v1.z+v1.w*v1.w;
  #pragma unroll
  for (int d=1; d<64; d<<=1) ss += __shfl_xor(ss, d);
  __shared__ float red[4];
  if ((tid&63)==0) red[tid>>6] = ss;
  __syncthreads();
  float rs = rsqrtf((red[0]+red[1]+red[2]+red[3]) * (1.0f/HD) + 1e-6f);
  const float* wp = w + tid*8;
  float a[8] = {v0.x,v0.y,v0.z,v0.w,v1.x,v1.y,v1.z,v1.w};
  uint4 o;
  o.x = (u32)f2bf(a[0]*rs*wp[0]) | ((u32)f2bf(a[1]*rs*wp[1])<<16);
  o.y = (u32)f2bf(a[2]*rs*wp[2]) | ((u32)f2bf(a[3]*rs*wp[3])<<16);
  o.z = (u32)f2bf(a[4]*rs*wp[4]) | ((u32)f2bf(a[5]*rs*wp[5])<<16);
  o.w = (u32)f2bf(a[6]*rs*wp[6]) | ((u32)f2bf(a[7]*rs*wp[7])<<16);
  ((uint4*)xn)[(size_t)t*(HD/8) + tid] = o;
}

// ---------------- Gate ----------------
__global__ __launch_bounds__(256) void k_gate(const float* __restrict__ x,
                                              const float* __restrict__ w,
                                              const float* __restrict__ gw,
                                              int* __restrict__ topk_id,
                                              float* __restrict__ topk_w,
                                              int* __restrict__ counts) {
  __shared__ float xs[HD];
  __shared__ float red[4];
  __shared__ float logits[NE];
  int t = blockIdx.x, tid = threadIdx.x;
  const float* row = x + (size_t)t*HD;
  float4 v0 = ((const float4*)row)[tid*2+0];
  float4 v1 = ((const float4*)row)[tid*2+1];
  float ss = v0.x*v0.x+v0.y*v0.y+v0.z*v0.z+v0.w*v0.w
           + v1.x*v1.x+v1.y*v1.y+v1.z*v1.z+v1.w*v1.w;
  #pragma unroll
  for (int d=1; d<64; d<<=1) ss += __shfl_xor(ss, d);
  if ((tid&63)==0) red[tid>>6] = ss;
  __syncthreads();
  float rs = 1.0f / sqrtf((red[0]+red[1]+red[2]+red[3]) * (1.0f/HD) + 1e-6f);
  const float* wp = w + tid*8;
  float a[8] = {v0.x,v0.y,v0.z,v0.w,v1.x,v1.y,v1.z,v1.w};
  #pragma unroll
  for (int j=0;j<8;++j) xs[tid*8+j] = a[j]*rs*wp[j];
  __syncthreads();
  int wave = tid>>6, lane = tid&63;
  for (int ei=0; ei<8; ++ei) {
    int e = wave*8 + ei;
    const float* g = gw + (size_t)e*HD;
    float s = 0.f;
    #pragma unroll
    for (int j=0;j<HD/64;++j) s += xs[lane + j*64] * g[lane + j*64];
    #pragma unroll
    for (int d=1; d<64; d<<=1) s += __shfl_xor(s, d);
    if (lane==0) logits[e] = s;
  }
  __syncthreads();
  if (tid==0) {
    float best[TOPK]; int bid[TOPK]; unsigned used = 0;
    for (int k2=0;k2<TOPK;++k2) {
      float bv = -1e30f; int bi = 0;
      for (int i2=0;i2<NE;++i2)
        if (!((used>>i2)&1u) && logits[i2] > bv) { bv = logits[i2]; bi = i2; }
      used |= 1u<<bi; best[k2] = bv; bid[k2] = bi;
    }
    float mx = best[0], sum = 0.f, wv[TOPK];
    for (int k2=0;k2<TOPK;++k2) { wv[k2] = expf(best[k2]-mx); sum += wv[k2]; }
    float inv = 1.f/sum;
    for (int k2=0;k2<TOPK;++k2) {
      topk_id[t*TOPK+k2] = bid[k2];
      topk_w[t*TOPK+k2] = wv[k2]*inv;
      atomicAdd(&counts[bid[k2]], 1);
    }
  }
}

__global__ void k_zero(int* counts, int* cursors) {
  int i = threadIdx.x;
  if (i < NE) { counts[i] = 0; cursors[i] = 0; }
}

__global__ void k_scan(const int* __restrict__ counts, int* __restrict__ starts) {
  if (threadIdx.x==0 && blockIdx.x==0) {
    int acc = 0;
    for (int e=0;e<NE;++e) { starts[e] = acc; acc += counts[e]; }
  }
}

__global__ __launch_bounds__(256) void k_dispatch(const int* __restrict__ topk_id,
                                                  const float* __restrict__ topk_w,
                                                  const int* __restrict__ starts,
                                                  int* __restrict__ cursors,
                                                  int* __restrict__ slot_tok,
                                                  float* __restrict__ slot_w) {
  int i = blockIdx.x*256 + threadIdx.x;
  int e = topk_id[i];
  int p = atomicAdd(&cursors[e], 1);
  int slot = starts[e] + p;
  slot_tok[slot] = i >> 2;
  slot_w[slot] = topk_w[i];
}

// B LDS layout (conflict-free, desk-checked):
//  256 staged cols x 32 ks, col-pair blocks of 128B:
//  addr_u16(c, q) = (c>>1)*64 + slot*4,  slot = (2q + (c&1)) ^ ((c>>2)&15), q = k>>2.
//  Writes (per instr): bank-pair = slot only (pair-block stride==0 mod 32 banks),
//  slot spans 16 values over 64 lanes -> 4 lanes/pair = b64 minimum. Reads same.
static __device__ __forceinline__ void packB(u16* Bb, int tq, int kb, const float4* bv) {
  int h = tq & 15;
  #pragma unroll
  for (int j = 0; j < 4; ++j) {
    int p = 2*tq + (j>>1);
    int cpar = j & 1;
    int s0 = ((4*kb + 0 + cpar) ^ h) * 4;
    int s1 = ((4*kb + 2 + cpar) ^ h) * 4;
    uint2 w0, w1;
    w0.x = cvtpk(((const float*)&bv[0])[j], ((const float*)&bv[1])[j]);
    w0.y = cvtpk(((const float*)&bv[2])[j], ((const float*)&bv[3])[j]);
    w1.x = cvtpk(((const float*)&bv[4])[j], ((const float*)&bv[5])[j]);
    w1.y = cvtpk(((const float*)&bv[6])[j], ((const float*)&bv[7])[j]);
    *(uint2*)&Bb[p*64 + s0] = w0;
    *(uint2*)&Bb[p*64 + s1] = w1;
  }
}

static __device__ __forceinline__ void loadB8(const float* bsrc, int ldb, float4* bv) {
  #pragma unroll
  for (int i = 0; i < 8; ++i) bv[i] = *(const float4*)(bsrc + (size_t)i*ldb);
}

// ============ GEMM up: wave-tile 128x64, 4 waves over 256 staged cols ============
template<bool INDEXED>
__global__ __launch_bounds__(256, 2) void k_gemm_up(
    const u16* __restrict__ A, int lda, int kiter,
    const float* __restrict__ Bg, const float* __restrict__ Bu,
    size_t bstride, int ldb,
    const int* __restrict__ counts, const int* __restrict__ starts,
    const int* __restrict__ slot_tok,
    u16* __restrict__ actOut) {
  __shared__ u16 Al[2][4096];
  __shared__ u16 Bl[2][8192];
  __shared__ int rowL[128];
  int t = threadIdx.x;
  int n0 = blockIdx.x * 128;          // output act cols per block
  int m0 = blockIdx.y * 128;
  int e  = blockIdx.z;
  int M, rowbase;
  if (INDEXED) { M = counts[e]; rowbase = starts[e]; if (m0 >= M) return; }
  else { M = NTOK; rowbase = 0; }
  if (t < 128) {
    int m = m0 + t;
    rowL[t] = INDEXED ? slot_tok[rowbase + (m < M ? m : M-1)] : m;
  }
  __syncthreads();
  // A staging (slots t, t+256): row=slot>>2, phys seg=slot&3, logical seg=phys^((row>>1)&3)
  int r0i = t>>2;
  int segA = ((t&3) ^ ((r0i>>1)&3)) << 3;
  const u16* srcA0 = A + (size_t)rowL[r0i]*lda + segA;
  const u16* srcA1 = A + (size_t)rowL[r0i+64]*lda + segA;
  // B staging: thread covers staged cols 4*tq..+3, ks kb*8..+7
  int tq = t & 63, kb = t >> 6;
  int sc4 = tq * 4;
  int isup = (sc4 >> 4) & 1;
  int og = ((sc4 >> 5) << 4) | (sc4 & 15);
  const float* bsrc = (isup ? Bu : Bg) + (INDEXED ? (size_t)e*bstride : 0)
                    + (size_t)(kb*8)*ldb + (n0 + og);

  int lane = t&63, wn = t>>6;
  int l15 = lane&15, l4 = lane>>4;
  // A frag offsets: frag f at aoffb + f*512
  int aoffb = l15*32 + ((l4 ^ ((l15>>1)&3))<<3);
  // B frag offsets
  int b0off[4];
  #pragma unroll
  for (int fn=0; fn<4; ++fn) {
    int pbase = wn*32 + fn*8 + (l15>>1);
    int h = (fn*4 + (l15>>2)) & 15;
    b0off[fn] = pbase*64 + (((4*l4 + (l15&1)) ^ h) << 2);
  }
  f32x4 acc[8][4];
  #pragma unroll
  for (int fm=0;fm<8;++fm)
    #pragma unroll
    for (int fn=0;fn<4;++fn)
      acc[fm][fn] = (f32x4){0.f,0.f,0.f,0.f};

  // prologue
  uint4 aA0 = *(const uint4*)srcA0, aA1 = *(const uint4*)srcA1;
  float4 bv[8]; loadB8(bsrc, ldb, bv);
  srcA0 += 32; srcA1 += 32; bsrc += (size_t)32*ldb;
  *(uint4*)&Al[0][t*8] = aA0;
  *(uint4*)&Al[0][2048 + t*8] = aA1;
  packB(Bl[0], tq, kb, bv);
  barrier_lgkm();

  int cur = 0;
  for (int kt = 0; kt < kiter; ++kt) {
    bool more = (kt+1 < kiter);
    if (more) {
      aA0 = *(const uint4*)srcA0; aA1 = *(const uint4*)srcA1;
      loadB8(bsrc, ldb, bv);
      srcA0 += 32; srcA1 += 32; bsrc += (size_t)32*ldb;
    }
    {
      bf16x8 bfr[4];
      #pragma unroll
      for (int fn=0; fn<4; ++fn) {
        uint2 lo = *(const uint2*)&Bl[cur][b0off[fn]];
        uint2 hi = *(const uint2*)&Bl[cur][b0off[fn] ^ 8];
        U32x4BF ub; ub.u = make_uint4(lo.x, lo.y, hi.x, hi.y);
        bfr[fn] = ub.h;
      }
      __builtin_amdgcn_s_setprio(1);
      #pragma unroll
      for (int fm=0; fm<8; ++fm) {
        bf16x8 af = *(const bf16x8*)&Al[cur][aoffb + fm*512];
        #pragma unroll
        for (int fn=0; fn<4; ++fn)
          acc[fm][fn] = __builtin_amdgcn_mfma_f32_16x16x32_bf16(af, bfr[fn], acc[fm][fn], 0,0,0);
      }
      __builtin_amdgcn_s_setprio(0);
    }
    if (more) {
      *(uint4*)&Al[cur^1][t*8] = aA0;
      *(uint4*)&Al[cur^1][2048 + t*8] = aA1;
      packB(Bl[cur^1], tq, kb, bv);
    }
    cur ^= 1;
    barrier_lgkm();
  }
  // epilogue: SwiGLU on (gate,up) fragment pairs
  #pragma unroll
  for (int fm=0; fm<8; ++fm) {
    #pragma unroll
    for (int fq=0; fq<2; ++fq) {
      f32x4 g = acc[fm][2*fq], u = acc[fm][2*fq+1];
      int col = n0 + (wn*2+fq)*16 + l15;
      #pragma unroll
      for (int r=0;r<4;++r) {
        int mloc = fm*16 + l4*4 + r;
        int m = m0 + mloc;
        if (m < M) {
          float gv = g[r];
          float av = gv / (1.f + expf(-gv)) * u[r];
          actOut[(size_t)(rowbase+m)*ID + col] = f2bf(av);
        }
      }
    }
  }
}

// ============ GEMM down: wave-tile 128x64, BN=256 ============
template<bool INDEXED>
__global__ __launch_bounds__(256, 2) void k_gemm_down(
    const u16* __restrict__ A, int lda, int kiter,
    const float* __restrict__ B, size_t bstride, int ldb,
    const int* __restrict__ counts, const int* __restrict__ starts,
    const int* __restrict__ slot_tok, const float* __restrict__ slot_w,
    const float* __restrict__ resid,
    float* __restrict__ out) {
  __shared__ u16 Al[2][4096];
  __shared__ u16 Bl[2][8192];
  __shared__ int tokL[128];
  __shared__ float wL[128];
  int t = threadIdx.x;
  int n0 = blockIdx.x * 256;
  int m0 = blockIdx.y * 128;
  int e  = blockIdx.z;
  int M, rowbase;
  if (INDEXED) { M = counts[e]; rowbase = starts[e]; if (m0 >= M) return; }
  else { M = NTOK; rowbase = 0; }
  if (INDEXED && t < 128) {
    int m = m0 + t;
    tokL[t] = (m<M) ? slot_tok[rowbase+m] : 0;
    wL[t]   = (m<M) ? slot_w[rowbase+m]  : 0.f;
  }
  if (INDEXED) __syncthreads();
  int r0i = t>>2;
  int segA = ((t&3) ^ ((r0i>>1)&3)) << 3;
  int am0 = m0 + r0i, am1 = m0 + r0i + 64;
  const u16* srcA0 = A + (size_t)(rowbase + (am0 < M ? am0 : M-1))*lda + segA;
  const u16* srcA1 = A + (size_t)(rowbase + (am1 < M ? am1 : M-1))*lda + segA;
  int tq = t & 63, kb = t >> 6;
  int sc4 = tq * 4;
  const float* bsrc = B + (INDEXED ? (size_t)e*bstride : 0)
                    + (size_t)(kb*8)*ldb + (n0 + sc4);

  int lane = t&63, wn = t>>6;
  int l15 = lane&15, l4 = lane>>4;
  int aoffb = l15*32 + ((l4 ^ ((l15>>1)&3))<<3);
  int b0off[4];
  #pragma unroll
  for (int fn=0; fn<4; ++fn) {
    int pbase = wn*32 + fn*8 + (l15>>1);
    int h = (fn*4 + (l15>>2)) & 15;
    b0off[fn] = pbase*64 + (((4*l4 + (l15&1)) ^ h) << 2);
  }
  f32x4 acc[8][4];
  #pragma unroll
  for (int fm=0;fm<8;++fm)
    #pragma unroll
    for (int fn=0;fn<4;++fn)
      acc[fm][fn] = (f32x4){0.f,0.f,0.f,0.f};

  uint4 aA0 = *(const uint4*)srcA0, aA1 = *(const uint4*)srcA1;
  float4 bv[8]; loadB8(bsrc, ldb, bv);
  srcA0 += 32; srcA1 += 32; bsrc += (size_t)32*ldb;
  *(uint4*)&Al[0][t*8] = aA0;
  *(uint4*)&Al[0][2048 + t*8] = aA1;
  packB(Bl[0], tq, kb, bv);
  barrier_lgkm();

  int cur = 0;
  for (int kt = 0; kt < kiter; ++kt) {
    bool more = (kt+1 < kiter);
    if (more) {
      aA0 = *(const uint4*)srcA0; aA1 = *(const uint4*)srcA1;
      loadB8(bsrc, ldb, bv);
      srcA0 += 32; srcA1 += 32; bsrc += (size_t)32*ldb;
    }
    {
      bf16x8 bfr[4];
      #pragma unroll
      for (int fn=0; fn<4; ++fn) {
        uint2 lo = *(const uint2*)&Bl[cur][b0off[fn]];
        uint2 hi = *(const uint2*)&Bl[cur][b0off[fn] ^ 8];
        U32x4BF ub; ub.u = make_uint4(lo.x, lo.y, hi.x, hi.y);
        bfr[fn] = ub.h;
      }
      __builtin_amdgcn_s_setprio(1);
      #pragma unroll
      for (int fm=0; fm<8; ++fm) {
        bf16x8 af = *(const bf16x8*)&Al[cur][aoffb + fm*512];
        #pragma unroll
        for (int fn=0; fn<4; ++fn)
          acc[fm][fn] = __builtin_amdgcn_mfma_f32_16x16x32_bf16(af, bfr[fn], acc[fm][fn], 0,0,0);
      }
      __builtin_amdgcn_s_setprio(0);
    }
    if (more) {
      *(uint4*)&Al[cur^1][t*8] = aA0;
      *(uint4*)&Al[cur^1][2048 + t*8] = aA1;
      packB(Bl[cur^1], tq, kb, bv);
    }
    cur ^= 1;
    barrier_lgkm();
  }
  #pragma unroll
  for (int fm=0; fm<8; ++fm) {
    #pragma unroll
    for (int fn=0; fn<4; ++fn) {
      f32x4 v = acc[fm][fn];
      int col = n0 + wn*64 + fn*16 + l15;
      #pragma unroll
      for (int r=0;r<4;++r) {
        int mloc = fm*16 + l4*4 + r;
        int m = m0 + mloc;
        if (m < M) {
          if (INDEXED) {
            atomicAdd(&out[(size_t)tokL[mloc]*HD + col], v[r]*wL[mloc]);
          } else {
            size_t o = (size_t)m*HD + col;
            out[o] = resid[o] + v[r];
          }
        }
      }
    }
  }
}

extern "C" void kernel_launch(void* const* d_in, const int* in_sizes, int n_in,
                              void* d_out, int out_size, void* d_ws, size_t ws_size,
                              hipStream_t stream) {
  const float* x    = (const float*)d_in[0];
  const float* nw   = (const float*)d_in[1];
  const float* gw   = (const float*)d_in[2];
  const float* w13  = (const float*)d_in[3];
  const float* w2   = (const float*)d_in[4];
  const float* sgw  = (const float*)d_in[5];
  const float* suw  = (const float*)d_in[6];
  const float* sdw  = (const float*)d_in[7];
  float* out = (float*)d_out;

  char* p = (char*)d_ws;
  u16* xn   = (u16*)p;  p += (size_t)NTOK*HD*2;
  u16* act  = (u16*)p;  p += (size_t)NSLOT*ID*2;
  u16* sact = (u16*)p;  p += (size_t)NTOK*ID*2;
  int*   topk_id  = (int*)p;   p += (size_t)NTOK*TOPK*4;
  float* topk_w   = (float*)p; p += (size_t)NTOK*TOPK*4;
  int*   slot_tok = (int*)p;   p += (size_t)NSLOT*4;
  float* slot_w   = (float*)p; p += (size_t)NSLOT*4;
  int*   counts   = (int*)p;   p += 64*4;
  int*   cursors  = (int*)p;   p += 64*4;
  int*   starts   = (int*)p;   p += 64*4;

  k_zero<<<1, 64, 0, stream>>>(counts, cursors);
  k_rmsnorm<<<NTOK, 256, 0, stream>>>(x, nw, xn);
  k_gate<<<NTOK, 256, 0, stream>>>(x, nw, gw, topk_id, topk_w, counts);
  k_scan<<<1, 1, 0, stream>>>(counts, starts);
  k_dispatch<<<NSLOT/256, 256, 0, stream>>>(topk_id, topk_w, starts, cursors, slot_tok, slot_w);

  // routed up-proj + swiglu: blocks of 128 rows x 128 act cols (256 staged)
  k_gemm_up<true><<<dim3(ID/128, 8, NE), 256, 0, stream>>>(
      xn, HD, HD/32, w13, w13 + ID, (size_t)HD*2*ID, 2*ID,
      counts, starts, slot_tok, act);
  // shared up-proj + swiglu
  k_gemm_up<false><<<dim3(ID/128, NTOK/128, 1), 256, 0, stream>>>(
      xn, HD, HD/32, sgw, suw, 0, ID, nullptr, nullptr, nullptr, sact);
  // shared down-proj: out = residual + shared
  k_gemm_down<false><<<dim3(HD/256, NTOK/128, 1), 256, 0, stream>>>(
      sact, ID, ID/32, sdw, 0, HD, nullptr, nullptr, nullptr, nullptr, x, out);
  // routed down-proj: atomic weighted scatter-add into out
  k_gemm_down<true><<<dim3(HD/256, 8, NE), 256, 0, stream>>>(
      act, ID, ID/32, w2, (size_t)ID*HD, HD, counts, starts, slot_tok, slot_w, nullptr, out);
}

// Round 9
// 758.834 us; speedup vs baseline: 1.1459x; 1.1459x over previous
//
#include <hip/hip_runtime.h>
#include <hip/hip_bf16.h>
#include <math.h>

#define HD 2048
#define ID 1024
#define NE 32
#define TOPK 4
#define NTOK 4096
#define NSLOT (NTOK*TOPK)

typedef __attribute__((ext_vector_type(4))) float f32x4;
typedef __attribute__((ext_vector_type(8))) short bf16x8;
typedef unsigned short u16;
typedef unsigned int u32;

union U32x4BF { uint4 u; bf16x8 h; };

static __device__ __forceinline__ u16 f2bf(float f) {
  union { float f; u32 u; } v; v.f = f;
  u32 r = v.u + 0x7fffu + ((v.u >> 16) & 1u);
  return (u16)(r >> 16);
}

static __device__ __forceinline__ u32 cvtpk(float lo, float hi) {
  u32 r;
  asm("v_cvt_pk_bf16_f32 %0, %1, %2" : "=v"(r) : "v"(lo), "v"(hi));
  return r;
}

static __device__ __forceinline__ void barrier_lgkm() {
  asm volatile("s_waitcnt lgkmcnt(0)" ::: "memory");
  __builtin_amdgcn_s_barrier();
}

// ---------------- RMSNorm -> bf16, also prefill out = residual ----------------
__global__ __launch_bounds__(256) void k_rmsnorm(const float* __restrict__ x,
                                                 const float* __restrict__ w,
                                                 u16* __restrict__ xn,
                                                 float* __restrict__ out) {
  int t = blockIdx.x, tid = threadIdx.x;
  const float* row = x + (size_t)t * HD;
  float4 v0 = ((const float4*)row)[tid*2+0];
  float4 v1 = ((const float4*)row)[tid*2+1];
  // residual prefill (down-proj kernels atomically accumulate on top)
  float* orow = out + (size_t)t * HD;
  ((float4*)orow)[tid*2+0] = v0;
  ((float4*)orow)[tid*2+1] = v1;
  float ss = v0.x*v0.x+v0.y*v0.y+v0.z*v0.z+v0.w*v0.w
           + v1.x*v1.x+v1.y*v1.y+v1.z*v1.z+v1.w*v1.w;
  #pragma unroll
  for (int d=1; d<64; d<<=1) ss += __shfl_xor(ss, d);
  __shared__ float red[4];
  if ((tid&63)==0) red[tid>>6] = ss;
  __syncthreads();
  float rs = rsqrtf((red[0]+red[1]+red[2]+red[3]) * (1.0f/HD) + 1e-6f);
  const float* wp = w + tid*8;
  float a[8] = {v0.x,v0.y,v0.z,v0.w,v1.x,v1.y,v1.z,v1.w};
  uint4 o;
  o.x = (u32)f2bf(a[0]*rs*wp[0]) | ((u32)f2bf(a[1]*rs*wp[1])<<16);
  o.y = (u32)f2bf(a[2]*rs*wp[2]) | ((u32)f2bf(a[3]*rs*wp[3])<<16);
  o.z = (u32)f2bf(a[4]*rs*wp[4]) | ((u32)f2bf(a[5]*rs*wp[5])<<16);
  o.w = (u32)f2bf(a[6]*rs*wp[6]) | ((u32)f2bf(a[7]*rs*wp[7])<<16);
  ((uint4*)xn)[(size_t)t*(HD/8) + tid] = o;
}

// ---------------- Gate ----------------
__global__ __launch_bounds__(256) void k_gate(const float* __restrict__ x,
                                              const float* __restrict__ w,
                                              const float* __restrict__ gw,
                                              int* __restrict__ topk_id,
                                              float* __restrict__ topk_w,
                                              int* __restrict__ counts) {
  __shared__ float xs[HD];
  __shared__ float red[4];
  __shared__ float logits[NE];
  int t = blockIdx.x, tid = threadIdx.x;
  const float* row = x + (size_t)t*HD;
  float4 v0 = ((const float4*)row)[tid*2+0];
  float4 v1 = ((const float4*)row)[tid*2+1];
  float ss = v0.x*v0.x+v0.y*v0.y+v0.z*v0.z+v0.w*v0.w
           + v1.x*v1.x+v1.y*v1.y+v1.z*v1.z+v1.w*v1.w;
  #pragma unroll
  for (int d=1; d<64; d<<=1) ss += __shfl_xor(ss, d);
  if ((tid&63)==0) red[tid>>6] = ss;
  __syncthreads();
  float rs = 1.0f / sqrtf((red[0]+red[1]+red[2]+red[3]) * (1.0f/HD) + 1e-6f);
  const float* wp = w + tid*8;
  float a[8] = {v0.x,v0.y,v0.z,v0.w,v1.x,v1.y,v1.z,v1.w};
  #pragma unroll
  for (int j=0;j<8;++j) xs[tid*8+j] = a[j]*rs*wp[j];
  __syncthreads();
  int wave = tid>>6, lane = tid&63;
  for (int ei=0; ei<8; ++ei) {
    int e = wave*8 + ei;
    const float* g = gw + (size_t)e*HD;
    float s = 0.f;
    #pragma unroll
    for (int j=0;j<HD/64;++j) s += xs[lane + j*64] * g[lane + j*64];
    #pragma unroll
    for (int d=1; d<64; d<<=1) s += __shfl_xor(s, d);
    if (lane==0) logits[e] = s;
  }
  __syncthreads();
  if (tid==0) {
    float best[TOPK]; int bid[TOPK]; unsigned used = 0;
    for (int k2=0;k2<TOPK;++k2) {
      float bv = -1e30f; int bi = 0;
      for (int i2=0;i2<NE;++i2)
        if (!((used>>i2)&1u) && logits[i2] > bv) { bv = logits[i2]; bi = i2; }
      used |= 1u<<bi; best[k2] = bv; bid[k2] = bi;
    }
    float mx = best[0], sum = 0.f, wv[TOPK];
    for (int k2=0;k2<TOPK;++k2) { wv[k2] = expf(best[k2]-mx); sum += wv[k2]; }
    float inv = 1.f/sum;
    for (int k2=0;k2<TOPK;++k2) {
      topk_id[t*TOPK+k2] = bid[k2];
      topk_w[t*TOPK+k2] = wv[k2]*inv;
      atomicAdd(&counts[bid[k2]], 1);
    }
  }
}

__global__ void k_zero(int* counts, int* cursors) {
  int i = threadIdx.x;
  if (i < NE) { counts[i] = 0; cursors[i] = 0; }
}

__global__ void k_scan(const int* __restrict__ counts, int* __restrict__ starts) {
  if (threadIdx.x==0 && blockIdx.x==0) {
    int acc = 0;
    for (int e=0;e<NE;++e) { starts[e] = acc; acc += counts[e]; }
  }
}

__global__ __launch_bounds__(256) void k_dispatch(const int* __restrict__ topk_id,
                                                  const float* __restrict__ topk_w,
                                                  const int* __restrict__ starts,
                                                  int* __restrict__ cursors,
                                                  int* __restrict__ slot_tok,
                                                  float* __restrict__ slot_w) {
  int i = blockIdx.x*256 + threadIdx.x;
  int e = topk_id[i];
  int p = atomicAdd(&cursors[e], 1);
  int slot = starts[e] + p;
  slot_tok[slot] = i >> 2;
  slot_w[slot] = topk_w[i];
}

// B LDS layout (conflict-free): 256 staged cols x 32 ks, col-pair 128B blocks:
//  addr_u16(c,q) = (c>>1)*64 + slot*4, slot = (2q+(c&1)) ^ ((c>>2)&15), q=k>>2.
static __device__ __forceinline__ void packB(u16* Bb, int tq, int kb, const float4* bv) {
  int h = tq & 15;
  #pragma unroll
  for (int j = 0; j < 4; ++j) {
    int p = 2*tq + (j>>1);
    int cpar = j & 1;
    int s0 = ((4*kb + 0 + cpar) ^ h) * 4;
    int s1 = ((4*kb + 2 + cpar) ^ h) * 4;
    uint2 w0, w1;
    w0.x = cvtpk(((const float*)&bv[0])[j], ((const float*)&bv[1])[j]);
    w0.y = cvtpk(((const float*)&bv[2])[j], ((const float*)&bv[3])[j]);
    w1.x = cvtpk(((const float*)&bv[4])[j], ((const float*)&bv[5])[j]);
    w1.y = cvtpk(((const float*)&bv[6])[j], ((const float*)&bv[7])[j]);
    *(uint2*)&Bb[p*64 + s0] = w0;
    *(uint2*)&Bb[p*64 + s1] = w1;
  }
}

static __device__ __forceinline__ void loadB8(const float* bsrc, int ldb, float4* bv) {
  #pragma unroll
  for (int i = 0; i < 8; ++i) bv[i] = *(const float4*)(bsrc + (size_t)i*ldb);
}

// ============ Fused up-GEMM + SwiGLU: z<NE routed experts, z==NE shared ============
__global__ __launch_bounds__(256, 2) void k_gemm_up(
    const u16* __restrict__ A, const float* __restrict__ w13,
    const float* __restrict__ sgw, const float* __restrict__ suw,
    const int* __restrict__ counts, const int* __restrict__ starts,
    const int* __restrict__ slot_tok,
    u16* __restrict__ act, u16* __restrict__ sact) {
  __shared__ u16 Al[2][4096];
  __shared__ u16 Bl[2][8192];
  __shared__ int rowL[128];
  int t = threadIdx.x;
  int n0 = blockIdx.x * 128;          // output act cols per block
  int m0 = blockIdx.y * 128;
  int e  = blockIdx.z;
  bool routed = (e < NE);
  int M, rowbase;
  u16* actOut;
  if (routed) { M = counts[e]; rowbase = starts[e]; actOut = act; if (m0 >= M) return; }
  else { M = NTOK; rowbase = 0; actOut = sact; }
  if (t < 128) {
    int m = m0 + t;
    rowL[t] = routed ? slot_tok[rowbase + (m < M ? m : M-1)] : m;
  }
  __syncthreads();
  int r0i = t>>2;
  int segA = ((t&3) ^ ((r0i>>1)&3)) << 3;
  const u16* srcA0 = A + (size_t)rowL[r0i]*HD + segA;
  const u16* srcA1 = A + (size_t)rowL[r0i+64]*HD + segA;
  // B staging: thread covers staged cols 4*tq..+3, ks kb*8..+7
  int tq = t & 63, kb = t >> 6;
  int sc4 = tq * 4;
  int isup = (sc4 >> 4) & 1;
  int og = ((sc4 >> 5) << 4) | (sc4 & 15);
  int ldb;
  const float* bsrc;
  if (routed) {
    ldb = 2*ID;
    const float* base = w13 + (size_t)e*HD*2*ID + (isup ? ID : 0);
    bsrc = base + (size_t)(kb*8)*ldb + (n0 + og);
  } else {
    ldb = ID;
    const float* base = isup ? suw : sgw;
    bsrc = base + (size_t)(kb*8)*ldb + (n0 + og);
  }

  int lane = t&63, wn = t>>6;
  int l15 = lane&15, l4 = lane>>4;
  int aoffb = l15*32 + ((l4 ^ ((l15>>1)&3))<<3);
  int b0off[4];
  #pragma unroll
  for (int fn=0; fn<4; ++fn) {
    int pbase = wn*32 + fn*8 + (l15>>1);
    int h = (fn*4 + (l15>>2)) & 15;
    b0off[fn] = pbase*64 + (((4*l4 + (l15&1)) ^ h) << 2);
  }
  f32x4 acc[8][4];
  #pragma unroll
  for (int fm=0;fm<8;++fm)
    #pragma unroll
    for (int fn=0;fn<4;++fn)
      acc[fm][fn] = (f32x4){0.f,0.f,0.f,0.f};

  uint4 aA0 = *(const uint4*)srcA0, aA1 = *(const uint4*)srcA1;
  float4 bv[8]; loadB8(bsrc, ldb, bv);
  srcA0 += 32; srcA1 += 32; bsrc += (size_t)32*ldb;
  *(uint4*)&Al[0][t*8] = aA0;
  *(uint4*)&Al[0][2048 + t*8] = aA1;
  packB(Bl[0], tq, kb, bv);
  barrier_lgkm();

  int cur = 0;
  const int kiter = HD/32;
  for (int kt = 0; kt < kiter; ++kt) {
    bool more = (kt+1 < kiter);
    if (more) {
      aA0 = *(const uint4*)srcA0; aA1 = *(const uint4*)srcA1;
      loadB8(bsrc, ldb, bv);
      srcA0 += 32; srcA1 += 32; bsrc += (size_t)32*ldb;
    }
    {
      bf16x8 bfr[4];
      #pragma unroll
      for (int fn=0; fn<4; ++fn) {
        uint2 lo = *(const uint2*)&Bl[cur][b0off[fn]];
        uint2 hi = *(const uint2*)&Bl[cur][b0off[fn] ^ 8];
        U32x4BF ub; ub.u = make_uint4(lo.x, lo.y, hi.x, hi.y);
        bfr[fn] = ub.h;
      }
      __builtin_amdgcn_s_setprio(1);
      #pragma unroll
      for (int fm=0; fm<8; ++fm) {
        bf16x8 af = *(const bf16x8*)&Al[cur][aoffb + fm*512];
        #pragma unroll
        for (int fn=0; fn<4; ++fn)
          acc[fm][fn] = __builtin_amdgcn_mfma_f32_16x16x32_bf16(af, bfr[fn], acc[fm][fn], 0,0,0);
      }
      __builtin_amdgcn_s_setprio(0);
    }
    if (more) {
      *(uint4*)&Al[cur^1][t*8] = aA0;
      *(uint4*)&Al[cur^1][2048 + t*8] = aA1;
      packB(Bl[cur^1], tq, kb, bv);
    }
    cur ^= 1;
    barrier_lgkm();
  }
  #pragma unroll
  for (int fm=0; fm<8; ++fm) {
    #pragma unroll
    for (int fq=0; fq<2; ++fq) {
      f32x4 g = acc[fm][2*fq], u = acc[fm][2*fq+1];
      int col = n0 + (wn*2+fq)*16 + l15;
      #pragma unroll
      for (int r=0;r<4;++r) {
        int mloc = fm*16 + l4*4 + r;
        int m = m0 + mloc;
        if (m < M) {
          float gv = g[r];
          float av = gv / (1.f + expf(-gv)) * u[r];
          actOut[(size_t)(rowbase+m)*ID + col] = f2bf(av);
        }
      }
    }
  }
}

// ============ Fused down-GEMM: z<NE routed (weighted), z==NE shared; all atomicAdd ============
__global__ __launch_bounds__(256, 2) void k_gemm_down(
    const u16* __restrict__ act, const u16* __restrict__ sact,
    const float* __restrict__ w2, const float* __restrict__ sdw,
    const int* __restrict__ counts, const int* __restrict__ starts,
    const int* __restrict__ slot_tok, const float* __restrict__ slot_w,
    float* __restrict__ out) {
  __shared__ u16 Al[2][4096];
  __shared__ u16 Bl[2][8192];
  __shared__ int tokL[128];
  __shared__ float wL[128];
  int t = threadIdx.x;
  int n0 = blockIdx.x * 256;
  int m0 = blockIdx.y * 128;
  int e  = blockIdx.z;
  bool routed = (e < NE);
  int M, rowbase;
  const u16* A;
  if (routed) { M = counts[e]; rowbase = starts[e]; A = act; if (m0 >= M) return; }
  else { M = NTOK; rowbase = 0; A = sact; }
  if (routed && t < 128) {
    int m = m0 + t;
    tokL[t] = (m<M) ? slot_tok[rowbase+m] : 0;
    wL[t]   = (m<M) ? slot_w[rowbase+m]  : 0.f;
  }
  if (routed) __syncthreads();
  int r0i = t>>2;
  int segA = ((t&3) ^ ((r0i>>1)&3)) << 3;
  int am0 = m0 + r0i, am1 = m0 + r0i + 64;
  const u16* srcA0 = A + (size_t)(rowbase + (am0 < M ? am0 : M-1))*ID + segA;
  const u16* srcA1 = A + (size_t)(rowbase + (am1 < M ? am1 : M-1))*ID + segA;
  int tq = t & 63, kb = t >> 6;
  int sc4 = tq * 4;
  const float* bsrc = (routed ? (w2 + (size_t)e*ID*HD) : sdw)
                    + (size_t)(kb*8)*HD + (n0 + sc4);

  int lane = t&63, wn = t>>6;
  int l15 = lane&15, l4 = lane>>4;
  int aoffb = l15*32 + ((l4 ^ ((l15>>1)&3))<<3);
  int b0off[4];
  #pragma unroll
  for (int fn=0; fn<4; ++fn) {
    int pbase = wn*32 + fn*8 + (l15>>1);
    int h = (fn*4 + (l15>>2)) & 15;
    b0off[fn] = pbase*64 + (((4*l4 + (l15&1)) ^ h) << 2);
  }
  f32x4 acc[8][4];
  #pragma unroll
  for (int fm=0;fm<8;++fm)
    #pragma unroll
    for (int fn=0;fn<4;++fn)
      acc[fm][fn] = (f32x4){0.f,0.f,0.f,0.f};

  uint4 aA0 = *(const uint4*)srcA0, aA1 = *(const uint4*)srcA1;
  float4 bv[8]; loadB8(bsrc, HD, bv);
  srcA0 += 32; srcA1 += 32; bsrc += (size_t)32*HD;
  *(uint4*)&Al[0][t*8] = aA0;
  *(uint4*)&Al[0][2048 + t*8] = aA1;
  packB(Bl[0], tq, kb, bv);
  barrier_lgkm();

  int cur = 0;
  const int kiter = ID/32;
  for (int kt = 0; kt < kiter; ++kt) {
    bool more = (kt+1 < kiter);
    if (more) {
      aA0 = *(const uint4*)srcA0; aA1 = *(const uint4*)srcA1;
      loadB8(bsrc, HD, bv);
      srcA0 += 32; srcA1 += 32; bsrc += (size_t)32*HD;
    }
    {
      bf16x8 bfr[4];
      #pragma unroll
      for (int fn=0; fn<4; ++fn) {
        uint2 lo = *(const uint2*)&Bl[cur][b0off[fn]];
        uint2 hi = *(const uint2*)&Bl[cur][b0off[fn] ^ 8];
        U32x4BF ub; ub.u = make_uint4(lo.x, lo.y, hi.x, hi.y);
        bfr[fn] = ub.h;
      }
      __builtin_amdgcn_s_setprio(1);
      #pragma unroll
      for (int fm=0; fm<8; ++fm) {
        bf16x8 af = *(const bf16x8*)&Al[cur][aoffb + fm*512];
        #pragma unroll
        for (int fn=0; fn<4; ++fn)
          acc[fm][fn] = __builtin_amdgcn_mfma_f32_16x16x32_bf16(af, bfr[fn], acc[fm][fn], 0,0,0);
      }
      __builtin_amdgcn_s_setprio(0);
    }
    if (more) {
      *(uint4*)&Al[cur^1][t*8] = aA0;
      *(uint4*)&Al[cur^1][2048 + t*8] = aA1;
      packB(Bl[cur^1], tq, kb, bv);
    }
    cur ^= 1;
    barrier_lgkm();
  }
  #pragma unroll
  for (int fm=0; fm<8; ++fm) {
    #pragma unroll
    for (int fn=0; fn<4; ++fn) {
      f32x4 v = acc[fm][fn];
      int col = n0 + wn*64 + fn*16 + l15;
      #pragma unroll
      for (int r=0;r<4;++r) {
        int mloc = fm*16 + l4*4 + r;
        int m = m0 + mloc;
        if (m < M) {
          if (routed) {
            atomicAdd(&out[(size_t)tokL[mloc]*HD + col], v[r]*wL[mloc]);
          } else {
            atomicAdd(&out[(size_t)m*HD + col], v[r]);
          }
        }
      }
    }
  }
}

extern "C" void kernel_launch(void* const* d_in, const int* in_sizes, int n_in,
                              void* d_out, int out_size, void* d_ws, size_t ws_size,
                              hipStream_t stream) {
  const float* x    = (const float*)d_in[0];
  const float* nw   = (const float*)d_in[1];
  const float* gw   = (const float*)d_in[2];
  const float* w13  = (const float*)d_in[3];
  const float* w2   = (const float*)d_in[4];
  const float* sgw  = (const float*)d_in[5];
  const float* suw  = (const float*)d_in[6];
  const float* sdw  = (const float*)d_in[7];
  float* out = (float*)d_out;

  char* p = (char*)d_ws;
  u16* xn   = (u16*)p;  p += (size_t)NTOK*HD*2;
  u16* act  = (u16*)p;  p += (size_t)NSLOT*ID*2;
  u16* sact = (u16*)p;  p += (size_t)NTOK*ID*2;
  int*   topk_id  = (int*)p;   p += (size_t)NTOK*TOPK*4;
  float* topk_w   = (float*)p; p += (size_t)NTOK*TOPK*4;
  int*   slot_tok = (int*)p;   p += (size_t)NSLOT*4;
  float* slot_w   = (float*)p; p += (size_t)NSLOT*4;
  int*   counts   = (int*)p;   p += 64*4;
  int*   cursors  = (int*)p;   p += 64*4;
  int*   starts   = (int*)p;   p += 64*4;

  k_zero<<<1, 64, 0, stream>>>(counts, cursors);
  k_rmsnorm<<<NTOK, 256, 0, stream>>>(x, nw, xn, out);
  k_gate<<<NTOK, 256, 0, stream>>>(x, nw, gw, topk_id, topk_w, counts);
  k_scan<<<1, 1, 0, stream>>>(counts, starts);
  k_dispatch<<<NSLOT/256, 256, 0, stream>>>(topk_id, topk_w, starts, cursors, slot_tok, slot_w);

  // fused up-proj + swiglu: z<NE routed experts, z==NE shared experts
  k_gemm_up<<<dim3(ID/128, 32, NE+1), 256, 0, stream>>>(
      xn, w13, sgw, suw, counts, starts, slot_tok, act, sact);
  // fused down-proj: all paths atomically accumulate onto residual-prefilled out
  k_gemm_down<<<dim3(HD/256, 32, NE+1), 256, 0, stream>>>(
      act, sact, w2, sdw, counts, starts, slot_tok, slot_w, out);
}

// Round 10
// 752.889 us; speedup vs baseline: 1.1550x; 1.0079x over previous
//
#include <hip/hip_runtime.h>
#include <hip/hip_bf16.h>
#include <math.h>

#define HD 2048
#define ID 1024
#define NE 32
#define TOPK 4
#define NTOK 4096
#define NSLOT (NTOK*TOPK)

typedef __attribute__((ext_vector_type(4))) float f32x4;
typedef __attribute__((ext_vector_type(8))) short bf16x8;
typedef unsigned short u16;
typedef unsigned int u32;

union U32x4BF { uint4 u; bf16x8 h; };

static __device__ __forceinline__ u16 f2bf(float f) {
  union { float f; u32 u; } v; v.f = f;
  u32 r = v.u + 0x7fffu + ((v.u >> 16) & 1u);
  return (u16)(r >> 16);
}

static __device__ __forceinline__ u32 cvtpk(float lo, float hi) {
  u32 r;
  asm("v_cvt_pk_bf16_f32 %0, %1, %2" : "=v"(r) : "v"(lo), "v"(hi));
  return r;
}

static __device__ __forceinline__ void barrier_lgkm() {
  asm volatile("s_waitcnt lgkmcnt(0)" ::: "memory");
  __builtin_amdgcn_s_barrier();
}

// B direct-to-reg: per lane 8 dwords per frag-column set (k = l4*8+j)
static __device__ __forceinline__ void loadBreg(const float* __restrict__ bg,
                                                const float* __restrict__ bu,
                                                u32 o0, u32 o1, u32 o2, u32 o3,
                                                u32 ldb, float bs[4][8]) {
  #pragma unroll
  for (int j = 0; j < 8; ++j) {
    bs[0][j] = bg[o0 + j*ldb];
    bs[1][j] = bu[o1 + j*ldb];
    bs[2][j] = bg[o2 + j*ldb];
    bs[3][j] = bu[o3 + j*ldb];
  }
}

static __device__ __forceinline__ void cvtB(const float bs[4][8], bf16x8 bfr[4]) {
  #pragma unroll
  for (int fn = 0; fn < 4; ++fn) {
    U32x4BF ub;
    ub.u.x = cvtpk(bs[fn][0], bs[fn][1]);
    ub.u.y = cvtpk(bs[fn][2], bs[fn][3]);
    ub.u.z = cvtpk(bs[fn][4], bs[fn][5]);
    ub.u.w = cvtpk(bs[fn][6], bs[fn][7]);
    bfr[fn] = ub.h;
  }
}

// ---------------- RMSNorm -> bf16, also prefill out = residual ----------------
__global__ __launch_bounds__(256) void k_rmsnorm(const float* __restrict__ x,
                                                 const float* __restrict__ w,
                                                 u16* __restrict__ xn,
                                                 float* __restrict__ out) {
  int t = blockIdx.x, tid = threadIdx.x;
  const float* row = x + (size_t)t * HD;
  float4 v0 = ((const float4*)row)[tid*2+0];
  float4 v1 = ((const float4*)row)[tid*2+1];
  float* orow = out + (size_t)t * HD;
  ((float4*)orow)[tid*2+0] = v0;
  ((float4*)orow)[tid*2+1] = v1;
  float ss = v0.x*v0.x+v0.y*v0.y+v0.z*v0.z+v0.w*v0.w
           + v1.x*v1.x+v1.y*v1.y+v1.z*v1.z+v1.w*v1.w;
  #pragma unroll
  for (int d=1; d<64; d<<=1) ss += __shfl_xor(ss, d);
  __shared__ float red[4];
  if ((tid&63)==0) red[tid>>6] = ss;
  __syncthreads();
  float rs = rsqrtf((red[0]+red[1]+red[2]+red[3]) * (1.0f/HD) + 1e-6f);
  const float* wp = w + tid*8;
  float a[8] = {v0.x,v0.y,v0.z,v0.w,v1.x,v1.y,v1.z,v1.w};
  uint4 o;
  o.x = (u32)f2bf(a[0]*rs*wp[0]) | ((u32)f2bf(a[1]*rs*wp[1])<<16);
  o.y = (u32)f2bf(a[2]*rs*wp[2]) | ((u32)f2bf(a[3]*rs*wp[3])<<16);
  o.z = (u32)f2bf(a[4]*rs*wp[4]) | ((u32)f2bf(a[5]*rs*wp[5])<<16);
  o.w = (u32)f2bf(a[6]*rs*wp[6]) | ((u32)f2bf(a[7]*rs*wp[7])<<16);
  ((uint4*)xn)[(size_t)t*(HD/8) + tid] = o;
}

// ---------------- Gate ----------------
__global__ __launch_bounds__(256) void k_gate(const float* __restrict__ x,
                                              const float* __restrict__ w,
                                              const float* __restrict__ gw,
                                              int* __restrict__ topk_id,
                                              float* __restrict__ topk_w,
                                              int* __restrict__ counts) {
  __shared__ float xs[HD];
  __shared__ float red[4];
  __shared__ float logits[NE];
  int t = blockIdx.x, tid = threadIdx.x;
  const float* row = x + (size_t)t*HD;
  float4 v0 = ((const float4*)row)[tid*2+0];
  float4 v1 = ((const float4*)row)[tid*2+1];
  float ss = v0.x*v0.x+v0.y*v0.y+v0.z*v0.z+v0.w*v0.w
           + v1.x*v1.x+v1.y*v1.y+v1.z*v1.z+v1.w*v1.w;
  #pragma unroll
  for (int d=1; d<64; d<<=1) ss += __shfl_xor(ss, d);
  if ((tid&63)==0) red[tid>>6] = ss;
  __syncthreads();
  float rs = 1.0f / sqrtf((red[0]+red[1]+red[2]+red[3]) * (1.0f/HD) + 1e-6f);
  const float* wp = w + tid*8;
  float a[8] = {v0.x,v0.y,v0.z,v0.w,v1.x,v1.y,v1.z,v1.w};
  #pragma unroll
  for (int j=0;j<8;++j) xs[tid*8+j] = a[j]*rs*wp[j];
  __syncthreads();
  int wave = tid>>6, lane = tid&63;
  for (int ei=0; ei<8; ++ei) {
    int e = wave*8 + ei;
    const float* g = gw + (size_t)e*HD;
    float s = 0.f;
    #pragma unroll
    for (int j=0;j<HD/64;++j) s += xs[lane + j*64] * g[lane + j*64];
    #pragma unroll
    for (int d=1; d<64; d<<=1) s += __shfl_xor(s, d);
    if (lane==0) logits[e] = s;
  }
  __syncthreads();
  if (tid==0) {
    float best[TOPK]; int bid[TOPK]; unsigned used = 0;
    for (int k2=0;k2<TOPK;++k2) {
      float bv = -1e30f; int bi = 0;
      for (int i2=0;i2<NE;++i2)
        if (!((used>>i2)&1u) && logits[i2] > bv) { bv = logits[i2]; bi = i2; }
      used |= 1u<<bi; best[k2] = bv; bid[k2] = bi;
    }
    float mx = best[0], sum = 0.f, wv[TOPK];
    for (int k2=0;k2<TOPK;++k2) { wv[k2] = expf(best[k2]-mx); sum += wv[k2]; }
    float inv = 1.f/sum;
    for (int k2=0;k2<TOPK;++k2) {
      topk_id[t*TOPK+k2] = bid[k2];
      topk_w[t*TOPK+k2] = wv[k2]*inv;
      atomicAdd(&counts[bid[k2]], 1);
    }
  }
}

__global__ void k_zero(int* counts, int* cursors) {
  int i = threadIdx.x;
  if (i < NE) { counts[i] = 0; cursors[i] = 0; }
}

__global__ void k_scan(const int* __restrict__ counts, int* __restrict__ starts) {
  if (threadIdx.x==0 && blockIdx.x==0) {
    int acc = 0;
    for (int e=0;e<NE;++e) { starts[e] = acc; acc += counts[e]; }
  }
}

__global__ __launch_bounds__(256) void k_dispatch(const int* __restrict__ topk_id,
                                                  const float* __restrict__ topk_w,
                                                  const int* __restrict__ starts,
                                                  int* __restrict__ cursors,
                                                  int* __restrict__ slot_tok,
                                                  float* __restrict__ slot_w) {
  int i = blockIdx.x*256 + threadIdx.x;
  int e = topk_id[i];
  int p = atomicAdd(&cursors[e], 1);
  int slot = starts[e] + p;
  slot_tok[slot] = i >> 2;
  slot_w[slot] = topk_w[i];
}

// ============ Fused up-GEMM + SwiGLU: z<NE routed experts, z==NE shared ============
// A: bf16 [*,HD] reg-staged -> LDS dbuf (XOR kseg, 2-way free). B: fp32 direct->reg frags.
__global__ __launch_bounds__(256, 2) void k_gemm_up(
    const u16* __restrict__ A, const float* __restrict__ w13,
    const float* __restrict__ sgw, const float* __restrict__ suw,
    const int* __restrict__ counts, const int* __restrict__ starts,
    const int* __restrict__ slot_tok,
    u16* __restrict__ act, u16* __restrict__ sact) {
  __shared__ u16 Al[2][4096];
  __shared__ int rowL[128];
  int t = threadIdx.x;
  int n0 = blockIdx.x * 128;
  int m0 = blockIdx.y * 128;
  int e  = blockIdx.z;
  bool routed = (e < NE);
  int M, rowbase;
  u16* actOut;
  if (routed) { M = counts[e]; rowbase = starts[e]; actOut = act; if (m0 >= M) return; }
  else { M = NTOK; rowbase = 0; actOut = sact; }
  if (t < 128) {
    int m = m0 + t;
    rowL[t] = routed ? slot_tok[rowbase + (m < M ? m : M-1)] : m;
  }
  __syncthreads();
  int r0i = t>>2;
  int segA = ((t&3) ^ ((r0i>>1)&3)) << 3;
  const u16* srcA0 = A + (size_t)rowL[r0i]*HD + segA;
  const u16* srcA1 = A + (size_t)rowL[r0i+64]*HD + segA;

  int lane = t&63, wn = t>>6;
  int l15 = lane&15, l4 = lane>>4;
  int aoffb = l15*32 + ((l4 ^ ((l15>>1)&3))<<3);

  // B addressing: uniform bases + per-lane u32 element offsets
  const float *bbg, *bbu;
  u32 ldb, o0, o1, o2, o3;
  {
    int c0 = n0 + (wn*2+0)*16 + l15;
    int c1 = n0 + (wn*2+1)*16 + l15;
    if (routed) {
      ldb = 2*ID;
      bbg = w13 + (size_t)e*HD*2*ID; bbu = bbg;
      u32 rb = (u32)(l4*8)*ldb;
      o0 = rb + c0; o1 = rb + c0 + ID; o2 = rb + c1; o3 = rb + c1 + ID;
    } else {
      ldb = ID;
      bbg = sgw; bbu = suw;
      u32 rb = (u32)(l4*8)*ldb;
      o0 = rb + c0; o1 = rb + c0; o2 = rb + c1; o3 = rb + c1;
    }
  }
  u32 kadv = 32*ldb;

  f32x4 acc[8][4];
  #pragma unroll
  for (int fm=0;fm<8;++fm)
    #pragma unroll
    for (int fn=0;fn<4;++fn)
      acc[fm][fn] = (f32x4){0.f,0.f,0.f,0.f};

  // prologue: tiles 0,1
  uint4 aA0 = *(const uint4*)srcA0, aA1 = *(const uint4*)srcA1;
  srcA0 += 32; srcA1 += 32;
  float bsA[4][8]; loadBreg(bbg, bbu, o0,o1,o2,o3, ldb, bsA);
  o0 += kadv; o1 += kadv; o2 += kadv; o3 += kadv;
  uint4 aB0 = *(const uint4*)srcA0, aB1 = *(const uint4*)srcA1;
  srcA0 += 32; srcA1 += 32;
  float bsB[4][8]; loadBreg(bbg, bbu, o0,o1,o2,o3, ldb, bsB);
  o0 += kadv; o1 += kadv; o2 += kadv; o3 += kadv;
  *(uint4*)&Al[0][t*8] = aA0;
  *(uint4*)&Al[0][2048 + t*8] = aA1;
  barrier_lgkm();

  const int kiter = HD/32;
  for (int kt = 0; kt < kiter; kt += 2) {
    // EVEN: compute tile kt (Al[0], bsA); prefetch tile kt+2 into A/bsA slots
    {
      bool pf = (kt+2 < kiter);
      if (pf) { aA0 = *(const uint4*)srcA0; aA1 = *(const uint4*)srcA1; srcA0 += 32; srcA1 += 32; }
      bf16x8 bfr[4]; cvtB(bsA, bfr);
      if (pf) { loadBreg(bbg, bbu, o0,o1,o2,o3, ldb, bsA);
                o0 += kadv; o1 += kadv; o2 += kadv; o3 += kadv; }
      __builtin_amdgcn_s_setprio(1);
      #pragma unroll
      for (int fm=0; fm<8; ++fm) {
        bf16x8 af = *(const bf16x8*)&Al[0][aoffb + fm*512];
        #pragma unroll
        for (int fn=0; fn<4; ++fn)
          acc[fm][fn] = __builtin_amdgcn_mfma_f32_16x16x32_bf16(af, bfr[fn], acc[fm][fn], 0,0,0);
      }
      __builtin_amdgcn_s_setprio(0);
      *(uint4*)&Al[1][t*8] = aB0;
      *(uint4*)&Al[1][2048 + t*8] = aB1;
      barrier_lgkm();
    }
    // ODD: compute tile kt+1 (Al[1], bsB); prefetch tile kt+3 into B slots
    {
      bool pf = (kt+3 < kiter);
      if (pf) { aB0 = *(const uint4*)srcA0; aB1 = *(const uint4*)srcA1; srcA0 += 32; srcA1 += 32; }
      bf16x8 bfr[4]; cvtB(bsB, bfr);
      if (pf) { loadBreg(bbg, bbu, o0,o1,o2,o3, ldb, bsB);
                o0 += kadv; o1 += kadv; o2 += kadv; o3 += kadv; }
      __builtin_amdgcn_s_setprio(1);
      #pragma unroll
      for (int fm=0; fm<8; ++fm) {
        bf16x8 af = *(const bf16x8*)&Al[1][aoffb + fm*512];
        #pragma unroll
        for (int fn=0; fn<4; ++fn)
          acc[fm][fn] = __builtin_amdgcn_mfma_f32_16x16x32_bf16(af, bfr[fn], acc[fm][fn], 0,0,0);
      }
      __builtin_amdgcn_s_setprio(0);
      if (kt+2 < kiter) {
        *(uint4*)&Al[0][t*8] = aA0;
        *(uint4*)&Al[0][2048 + t*8] = aA1;
      }
      barrier_lgkm();
    }
  }
  // epilogue: SwiGLU on (gate,up) fragment pairs
  #pragma unroll
  for (int fm=0; fm<8; ++fm) {
    #pragma unroll
    for (int fq=0; fq<2; ++fq) {
      f32x4 g = acc[fm][2*fq], u = acc[fm][2*fq+1];
      int col = n0 + (wn*2+fq)*16 + l15;
      #pragma unroll
      for (int r=0;r<4;++r) {
        int mloc = fm*16 + l4*4 + r;
        int m = m0 + mloc;
        if (m < M) {
          float gv = g[r];
          float av = gv / (1.f + expf(-gv)) * u[r];
          actOut[(size_t)(rowbase+m)*ID + col] = f2bf(av);
        }
      }
    }
  }
}

// ============ Fused down-GEMM: z<NE routed (weighted), z==NE shared; atomicAdd ============
__global__ __launch_bounds__(256, 2) void k_gemm_down(
    const u16* __restrict__ act, const u16* __restrict__ sact,
    const float* __restrict__ w2, const float* __restrict__ sdw,
    const int* __restrict__ counts, const int* __restrict__ starts,
    const int* __restrict__ slot_tok, const float* __restrict__ slot_w,
    float* __restrict__ out) {
  __shared__ u16 Al[2][4096];
  __shared__ int tokL[128];
  __shared__ float wL[128];
  int t = threadIdx.x;
  int n0 = blockIdx.x * 256;
  int m0 = blockIdx.y * 128;
  int e  = blockIdx.z;
  bool routed = (e < NE);
  int M, rowbase;
  const u16* A;
  if (routed) { M = counts[e]; rowbase = starts[e]; A = act; if (m0 >= M) return; }
  else { M = NTOK; rowbase = 0; A = sact; }
  if (routed && t < 128) {
    int m = m0 + t;
    tokL[t] = (m<M) ? slot_tok[rowbase+m] : 0;
    wL[t]   = (m<M) ? slot_w[rowbase+m]  : 0.f;
  }
  if (routed) __syncthreads();
  int r0i = t>>2;
  int segA = ((t&3) ^ ((r0i>>1)&3)) << 3;
  int am0 = m0 + r0i, am1 = m0 + r0i + 64;
  const u16* srcA0 = A + (size_t)(rowbase + (am0 < M ? am0 : M-1))*ID + segA;
  const u16* srcA1 = A + (size_t)(rowbase + (am1 < M ? am1 : M-1))*ID + segA;

  int lane = t&63, wn = t>>6;
  int l15 = lane&15, l4 = lane>>4;
  int aoffb = l15*32 + ((l4 ^ ((l15>>1)&3))<<3);

  const float* bb = routed ? (w2 + (size_t)e*ID*HD) : sdw;
  const u32 ldb = HD;
  u32 rb = (u32)(l4*8)*ldb;
  u32 o0 = rb + n0 + wn*64 + 0*16 + l15;
  u32 o1 = rb + n0 + wn*64 + 1*16 + l15;
  u32 o2 = rb + n0 + wn*64 + 2*16 + l15;
  u32 o3 = rb + n0 + wn*64 + 3*16 + l15;
  const u32 kadv = 32*ldb;

  f32x4 acc[8][4];
  #pragma unroll
  for (int fm=0;fm<8;++fm)
    #pragma unroll
    for (int fn=0;fn<4;++fn)
      acc[fm][fn] = (f32x4){0.f,0.f,0.f,0.f};

  uint4 aA0 = *(const uint4*)srcA0, aA1 = *(const uint4*)srcA1;
  srcA0 += 32; srcA1 += 32;
  float bsA[4][8]; loadBreg(bb, bb, o0,o1,o2,o3, ldb, bsA);
  o0 += kadv; o1 += kadv; o2 += kadv; o3 += kadv;
  uint4 aB0 = *(const uint4*)srcA0, aB1 = *(const uint4*)srcA1;
  srcA0 += 32; srcA1 += 32;
  float bsB[4][8]; loadBreg(bb, bb, o0,o1,o2,o3, ldb, bsB);
  o0 += kadv; o1 += kadv; o2 += kadv; o3 += kadv;
  *(uint4*)&Al[0][t*8] = aA0;
  *(uint4*)&Al[0][2048 + t*8] = aA1;
  barrier_lgkm();

  const int kiter = ID/32;
  for (int kt = 0; kt < kiter; kt += 2) {
    {
      bool pf = (kt+2 < kiter);
      if (pf) { aA0 = *(const uint4*)srcA0; aA1 = *(const uint4*)srcA1; srcA0 += 32; srcA1 += 32; }
      bf16x8 bfr[4]; cvtB(bsA, bfr);
      if (pf) { loadBreg(bb, bb, o0,o1,o2,o3, ldb, bsA);
                o0 += kadv; o1 += kadv; o2 += kadv; o3 += kadv; }
      __builtin_amdgcn_s_setprio(1);
      #pragma unroll
      for (int fm=0; fm<8; ++fm) {
        bf16x8 af = *(const bf16x8*)&Al[0][aoffb + fm*512];
        #pragma unroll
        for (int fn=0; fn<4; ++fn)
          acc[fm][fn] = __builtin_amdgcn_mfma_f32_16x16x32_bf16(af, bfr[fn], acc[fm][fn], 0,0,0);
      }
      __builtin_amdgcn_s_setprio(0);
      *(uint4*)&Al[1][t*8] = aB0;
      *(uint4*)&Al[1][2048 + t*8] = aB1;
      barrier_lgkm();
    }
    {
      bool pf = (kt+3 < kiter);
      if (pf) { aB0 = *(const uint4*)srcA0; aB1 = *(const uint4*)srcA1; srcA0 += 32; srcA1 += 32; }
      bf16x8 bfr[4]; cvtB(bsB, bfr);
      if (pf) { loadBreg(bb, bb, o0,o1,o2,o3, ldb, bsB);
                o0 += kadv; o1 += kadv; o2 += kadv; o3 += kadv; }
      __builtin_amdgcn_s_setprio(1);
      #pragma unroll
      for (int fm=0; fm<8; ++fm) {
        bf16x8 af = *(const bf16x8*)&Al[1][aoffb + fm*512];
        #pragma unroll
        for (int fn=0; fn<4; ++fn)
          acc[fm][fn] = __builtin_amdgcn_mfma_f32_16x16x32_bf16(af, bfr[fn], acc[fm][fn], 0,0,0);
      }
      __builtin_amdgcn_s_setprio(0);
      if (kt+2 < kiter) {
        *(uint4*)&Al[0][t*8] = aA0;
        *(uint4*)&Al[0][2048 + t*8] = aA1;
      }
      barrier_lgkm();
    }
  }
  #pragma unroll
  for (int fm=0; fm<8; ++fm) {
    #pragma unroll
    for (int fn=0; fn<4; ++fn) {
      f32x4 v = acc[fm][fn];
      int col = n0 + wn*64 + fn*16 + l15;
      #pragma unroll
      for (int r=0;r<4;++r) {
        int mloc = fm*16 + l4*4 + r;
        int m = m0 + mloc;
        if (m < M) {
          if (routed) {
            atomicAdd(&out[(size_t)tokL[mloc]*HD + col], v[r]*wL[mloc]);
          } else {
            atomicAdd(&out[(size_t)m*HD + col], v[r]);
          }
        }
      }
    }
  }
}

extern "C" void kernel_launch(void* const* d_in, const int* in_sizes, int n_in,
                              void* d_out, int out_size, void* d_ws, size_t ws_size,
                              hipStream_t stream) {
  const float* x    = (const float*)d_in[0];
  const float* nw   = (const float*)d_in[1];
  const float* gw   = (const float*)d_in[2];
  const float* w13  = (const float*)d_in[3];
  const float* w2   = (const float*)d_in[4];
  const float* sgw  = (const float*)d_in[5];
  const float* suw  = (const float*)d_in[6];
  const float* sdw  = (const float*)d_in[7];
  float* out = (float*)d_out;

  char* p = (char*)d_ws;
  u16* xn   = (u16*)p;  p += (size_t)NTOK*HD*2;
  u16* act  = (u16*)p;  p += (size_t)NSLOT*ID*2;
  u16* sact = (u16*)p;  p += (size_t)NTOK*ID*2;
  int*   topk_id  = (int*)p;   p += (size_t)NTOK*TOPK*4;
  float* topk_w   = (float*)p; p += (size_t)NTOK*TOPK*4;
  int*   slot_tok = (int*)p;   p += (size_t)NSLOT*4;
  float* slot_w   = (float*)p; p += (size_t)NSLOT*4;
  int*   counts   = (int*)p;   p += 64*4;
  int*   cursors  = (int*)p;   p += 64*4;
  int*   starts   = (int*)p;   p += 64*4;

  k_zero<<<1, 64, 0, stream>>>(counts, cursors);
  k_rmsnorm<<<NTOK, 256, 0, stream>>>(x, nw, xn, out);
  k_gate<<<NTOK, 256, 0, stream>>>(x, nw, gw, topk_id, topk_w, counts);
  k_scan<<<1, 1, 0, stream>>>(counts, starts);
  k_dispatch<<<NSLOT/256, 256, 0, stream>>>(topk_id, topk_w, starts, cursors, slot_tok, slot_w);

  // fused up-proj + swiglu: z<NE routed experts, z==NE shared experts
  k_gemm_up<<<dim3(ID/128, 32, NE+1), 256, 0, stream>>>(
      xn, w13, sgw, suw, counts, starts, slot_tok, act, sact);
  // fused down-proj: all paths atomically accumulate onto residual-prefilled out
  k_gemm_down<<<dim3(HD/256, 32, NE+1), 256, 0, stream>>>(
      act, sact, w2, sdw, counts, starts, slot_tok, slot_w, out);
}